// Round 11
// baseline (122.308 us; speedup 1.0000x reference)
//
#include <hip/hip_runtime.h>
#include <hip/hip_bf16.h>
#include <cstddef>

// Problem constants (EmbeddingEngine_47029891891415)
#define S_ 4
#define N_ 65536
#define K_ 64
#define D_ 256
#define P_ 8192

typedef __bf16 bf16x8 __attribute__((ext_vector_type(8)));
typedef float  f32x4  __attribute__((ext_vector_type(4)));

// Pack W [S][K=64][D=256] fp32 -> bf16 MFMA fragments in ws.
// wpack[(((s*2 + t)*16 + c)*64 + lane)*8 + i] =
//     bf16(W[s][t*32 + 8*(lane>>4) + i][c*16 + (lane&15)])
__global__ __launch_bounds__(256) void pack_w_kernel(const float* __restrict__ W,
                                                     __bf16* __restrict__ wpack) {
    int tid  = blockIdx.x * 256 + threadIdx.x;   // 0..65535
    int i    =  tid        & 7;
    int lane = (tid >> 3)  & 63;
    int c    = (tid >> 9)  & 15;
    int t    = (tid >> 13) & 1;
    int s    =  tid >> 14;
    int k    = t * 32 + 8 * (lane >> 4) + i;
    int col  = c * 16 + (lane & 15);
    wpack[tid] = (__bf16)W[(s * K_ + k) * D_ + col];
}

// R10 base, restructured for occupancy (the single remaining theory:
// latency-bound at 16 waves/CU, LDS+VGPR capped).
//  - 4 sequential quarter-GEMMs: acc[4] (16 VGPR) instead of acc[16] (64).
//    wpack re-streams from L2 (cheap). Target ~60 VGPR -> 8 waves/SIMD.
//  - Per-quarter LDS staging [16][72] (stride 72: 18j mod 32 bijective over
//    j=0..15 -> conflict-free ds_write) = 18.4 KB/block -> 8 blocks/CU.
//  -> resident waves/CU 16 -> ~32.
// All R10-proven elements kept: NT token loads, LDS-transposed CONTIGUOUS
// NT store bursts (4 rows x 256B per instr), swapped-operand MFMA
// (C/D m89/m91: col(lane&15)=token, row(g*4+reg)=d_local), fp32 pe gathers
// in epilogue position.
__global__ __launch_bounds__(256) void embed_kernel(
        const float* __restrict__ tokens,    // [S][N][K] f32
        const float* __restrict__ bvec,      // [S][D] f32
        const float* __restrict__ pe,        // [P][D] f32
        const int*   __restrict__ idxs,      // [S][N] i32
        const int*   __restrict__ idxs_pe,   // [S][N] i32
        const __bf16* __restrict__ wpack,    // packed W fragments (L2)
        float* __restrict__ out) {           // [S*N][D] f32
    const int blk   = blockIdx.x;            // 0..4095
    const int s     = blk >> 10;             // 1024 tiles per stream
    const int tile  = blk & 1023;
    const int wave  = threadIdx.x >> 6;
    const int lane  = threadIdx.x & 63;
    const int j     = lane & 15;             // token within wave tile
    const int g     = lane >> 4;
    const int rowbase = tile * 64 + wave * 16;
    const int trowi   = rowbase + j;         // token row within stream

    __shared__ float lds[4][16][72];         // per-wave [row][64+8 pad]
    float* const wl = &lds[wave][0][0];

    // ---- token fragments: tok[trowi][k], k = t*32 + 8g + e (streaming)
    const float* trow = tokens + ((size_t)s * N_ + trowi) * K_;
    f32x4 t0lo = __builtin_nontemporal_load((const f32x4*)(trow +      8 * g));
    f32x4 t0hi = __builtin_nontemporal_load((const f32x4*)(trow +      8 * g + 4));
    f32x4 t1lo = __builtin_nontemporal_load((const f32x4*)(trow + 32 + 8 * g));
    f32x4 t1hi = __builtin_nontemporal_load((const f32x4*)(trow + 32 + 8 * g + 4));
    bf16x8 a0, a1;
#pragma unroll
    for (int e = 0; e < 4; ++e) {
        a0[e]     = (__bf16)t0lo[e];
        a0[e + 4] = (__bf16)t0hi[e];
        a1[e]     = (__bf16)t1lo[e];
        a1[e + 4] = (__bf16)t1hi[e];
    }

    const bf16x8* wp0 = (const bf16x8*)wpack + (size_t)((s * 2 + 0) * 16) * 64;
    const bf16x8* wp1 = (const bf16x8*)wpack + (size_t)((s * 2 + 1) * 16) * 64;
    const int ipe = idxs_pe[s * N_ + trowi];
    const float* __restrict__ perow = pe + (size_t)ipe * D_ + g * 4;
    const float* __restrict__ brow  = bvec + s * D_ + g * 4;
    const int q2 = lane >> 4;                // row sub-index for store phase
    const int lo = lane & 15;                // 16-lane 256B row cover

#pragma unroll
    for (int q = 0; q < 4; ++q) {
        // --- quarter-GEMM: cols q*64 .. q*64+63 (fragments q*4..q*4+3)
        f32x4 acc[4];
#pragma unroll
        for (int cc = 0; cc < 4; ++cc) acc[cc] = (f32x4){0.f, 0.f, 0.f, 0.f};
#pragma unroll
        for (int cc = 0; cc < 4; ++cc) {
            const int c = q * 4 + cc;
            bf16x8 w0 = wp0[c * 64 + lane];
            bf16x8 w1 = wp1[c * 64 + lane];
            acc[cc] = __builtin_amdgcn_mfma_f32_16x16x32_bf16(w0, a0, acc[cc], 0, 0, 0);
            acc[cc] = __builtin_amdgcn_mfma_f32_16x16x32_bf16(w1, a1, acc[cc], 0, 0, 0);
        }
        // --- gather pe + bias, stage into LDS (wave-private, lgkmcnt-ordered)
#pragma unroll
        for (int cc = 0; cc < 4; ++cc) {
            const int c = q * 4 + cc;
            f32x4 pev = *(const f32x4*)(perow + c * 16);
            f32x4 bbv = *(const f32x4*)(brow  + c * 16);
            f32x4 o   = acc[cc] + bbv + pev;
            *(f32x4*)(wl + j * 72 + cc * 16 + g * 4) = o;
        }
        // --- contiguous NT store burst: 4 instrs, each 4 rows x 256B
#pragma unroll
        for (int i = 0; i < 4; ++i) {
            const int r      = i * 4 + q2;
            const int orow_r = idxs[s * N_ + rowbase + r];
            f32x4 v = *(const f32x4*)(wl + r * 72 + lo * 4);
            __builtin_nontemporal_store(
                v, (f32x4*)(out + (size_t)orow_r * D_ + q * 64 + lo * 4));
        }
    }
}

extern "C" void kernel_launch(void* const* d_in, const int* in_sizes, int n_in,
                              void* d_out, int out_size, void* d_ws, size_t ws_size,
                              hipStream_t stream) {
    const float* tokens  = (const float*)d_in[0];
    const float* W       = (const float*)d_in[1];
    const float* bvec    = (const float*)d_in[2];
    const float* pe      = (const float*)d_in[3];
    const int*   idxs    = (const int*)d_in[4];
    const int*   idxs_pe = (const int*)d_in[5];
    float* out = (float*)d_out;
    __bf16* wpack = (__bf16*)d_ws;   // 128 KB

    pack_w_kernel<<<256, 256, 0, stream>>>(W, wpack);
    embed_kernel<<<S_ * (N_ / 64), 256, 0, stream>>>(tokens, bvec, pe, idxs, idxs_pe,
                                                     wpack, out);
}